// Round 1
// baseline (377.944 us; speedup 1.0000x reference)
//
#include <hip/hip_runtime.h>
#include <cstdint>
#include <cstddef>

#define Bb 4
#define Tt 2048
#define Ssz 2048
#define Cc 256
#define Ee 512
#define Hh 8
#define Dd 64

typedef short bf8 __attribute__((ext_vector_type(8)));
typedef float f4 __attribute__((ext_vector_type(4)));

__device__ __forceinline__ unsigned short f2bf(float x) {
  unsigned int u = __float_as_uint(x);
  u += 0x7fffu + ((u >> 16) & 1u);
  return (unsigned short)(u >> 16);
}
__device__ __forceinline__ float bf2f(unsigned short h) {
  return __uint_as_float(((unsigned int)h) << 16);
}

// ---------------- fp32 -> bf16 cast (vectorized) ----------------
__global__ __launch_bounds__(256) void castk(const float* __restrict__ s,
                                             unsigned short* __restrict__ d,
                                             int n4) {
  int i = blockIdx.x * 256 + threadIdx.x;
  if (i < n4) {
    float4 v = ((const float4*)s)[i];
    ushort4 o;
    o.x = f2bf(v.x);
    o.y = f2bf(v.y);
    o.z = f2bf(v.z);
    o.w = f2bf(v.w);
    ((ushort4*)d)[i] = o;
  }
}

// ---------------- GEMM: C[M,N] = A[M,K] * Bt[N,K]^T + bias ----------------
// 128x128 tile, BK=64, 256 threads (4 waves as 2x2, each wave 64x64 = 4x4 mfma frags)
template <bool OUT_BF16>
__global__ __launch_bounds__(256) void gemm_bt(const unsigned short* __restrict__ A,
                                               const unsigned short* __restrict__ Bt,
                                               const float* __restrict__ bias,
                                               void* __restrict__ Cout,
                                               int M, int N, int K) {
  __shared__ unsigned short As[128][72];
  __shared__ unsigned short Bs[128][72];
  const int tid = threadIdx.x;
  const int wave = tid >> 6, lane = tid & 63;
  const int wm = (wave >> 1) * 64, wn = (wave & 1) * 64;
  const int lrow = lane & 15, quad = lane >> 4;
  const int m0 = blockIdx.x * 128, n0 = blockIdx.y * 128;

  f4 acc[4][4];
#pragma unroll
  for (int i = 0; i < 4; i++)
#pragma unroll
    for (int j = 0; j < 4; j++) {
      f4 z = {0.f, 0.f, 0.f, 0.f};
      acc[i][j] = z;
    }

  for (int k0 = 0; k0 < K; k0 += 64) {
#pragma unroll
    for (int i = 0; i < 4; i++) {
      int id = tid + i * 256;
      int row = id >> 3, cc = id & 7;
      bf8 av = *(const bf8*)(A + (size_t)(m0 + row) * K + k0 + cc * 8);
      *(bf8*)&As[row][cc * 8] = av;
      bf8 bv = *(const bf8*)(Bt + (size_t)(n0 + row) * K + k0 + cc * 8);
      *(bf8*)&Bs[row][cc * 8] = bv;
    }
    __syncthreads();
#pragma unroll
    for (int kk = 0; kk < 2; kk++) {
      bf8 af[4], bff[4];
#pragma unroll
      for (int i = 0; i < 4; i++)
        af[i] = *(const bf8*)&As[wm + i * 16 + lrow][kk * 32 + quad * 8];
#pragma unroll
      for (int j = 0; j < 4; j++)
        bff[j] = *(const bf8*)&Bs[wn + j * 16 + lrow][kk * 32 + quad * 8];
#pragma unroll
      for (int i = 0; i < 4; i++)
#pragma unroll
        for (int j = 0; j < 4; j++)
          acc[i][j] = __builtin_amdgcn_mfma_f32_16x16x32_bf16(af[i], bff[j],
                                                              acc[i][j], 0, 0, 0);
    }
    __syncthreads();
  }

#pragma unroll
  for (int j = 0; j < 4; j++) {
    int col = n0 + wn + j * 16 + lrow;
    float bvv = bias ? bias[col] : 0.f;
#pragma unroll
    for (int i = 0; i < 4; i++) {
#pragma unroll
      for (int r = 0; r < 4; r++) {
        int row = m0 + wm + i * 16 + quad * 4 + r;
        float v = acc[i][j][r] + bvv;
        if (OUT_BF16)
          ((unsigned short*)Cout)[(size_t)row * N + col] = f2bf(v);
        else
          ((float*)Cout)[(size_t)row * N + col] = v;
      }
    }
  }
}

// ---------------- fused masked cross-attention ----------------
// grid (T/64, H, B), 256 threads. Per block: 64 Q-rows, loop S in 64-tiles.
// Unnormalized softmax (logits are O(0.1): no max subtraction needed).
__global__ __launch_bounds__(256) void attn(const unsigned short* __restrict__ Q,
                                            const unsigned short* __restrict__ K,
                                            const unsigned short* __restrict__ V,
                                            const int* __restrict__ mask,
                                            unsigned short* __restrict__ O) {
  __shared__ unsigned short Qs[64][72];
  __shared__ unsigned short Ks[64][72];
  __shared__ unsigned short Vts[64][72];  // V^T: [d][s]
  __shared__ unsigned short Ps[64][72];
  const int tid = threadIdx.x;
  const int wave = tid >> 6, lane = tid & 63;
  const int lrow = lane & 15, quad = lane >> 4;
  const int b = blockIdx.z, h = blockIdx.y, t0 = blockIdx.x * 64;
  const float scale = 0.044194173824159216f;  // 512^-0.5

  // stage Q tile (64 rows x 64 d)
#pragma unroll
  for (int i = 0; i < 2; i++) {
    int id = tid + i * 256;
    int row = id >> 3, cc = id & 7;
    *(bf8*)&Qs[row][cc * 8] =
        *(const bf8*)(Q + (size_t)(b * Tt + t0 + row) * Ee + h * 64 + cc * 8);
  }
  __syncthreads();
  bf8 qf0 = *(const bf8*)&Qs[wave * 16 + lrow][quad * 8];
  bf8 qf1 = *(const bf8*)&Qs[wave * 16 + lrow][32 + quad * 8];

  f4 oacc[4];
#pragma unroll
  for (int j = 0; j < 4; j++) {
    f4 z = {0.f, 0.f, 0.f, 0.f};
    oacc[j] = z;
  }
  float dsum[4] = {0.f, 0.f, 0.f, 0.f};
  const int trow = t0 + wave * 16 + quad * 4;  // first of this lane's 4 rows

  for (int s0 = 0; s0 < Ssz; s0 += 64) {
    __syncthreads();
    // stage K tile and transposed V tile
#pragma unroll
    for (int i = 0; i < 2; i++) {
      int id = tid + i * 256;
      int row = id >> 3, cc = id & 7;
      *(bf8*)&Ks[row][cc * 8] =
          *(const bf8*)(K + (size_t)(b * Ssz + s0 + row) * Ee + h * 64 + cc * 8);
      int vcc = wave * 2 + i;  // per-wave-constant d-chunk -> conflict-free writes
      bf8 vv = *(const bf8*)(V + (size_t)(b * Ssz + s0 + lane) * Ee + h * 64 + vcc * 8);
#pragma unroll
      for (int jj = 0; jj < 8; jj++)
        Vts[vcc * 8 + jj][lane] = (unsigned short)vv[jj];
    }
    __syncthreads();

    float prt[4] = {0.f, 0.f, 0.f, 0.f};
#pragma unroll
    for (int j = 0; j < 4; j++) {
      f4 sacc = {0.f, 0.f, 0.f, 0.f};
      sacc = __builtin_amdgcn_mfma_f32_16x16x32_bf16(
          qf0, *(const bf8*)&Ks[j * 16 + lrow][quad * 8], sacc, 0, 0, 0);
      sacc = __builtin_amdgcn_mfma_f32_16x16x32_bf16(
          qf1, *(const bf8*)&Ks[j * 16 + lrow][32 + quad * 8], sacc, 0, 0, 0);
      int col = j * 16 + lrow;
      const int* mrow = mask + (size_t)(b * Tt + trow) * Ssz + s0 + col;
#pragma unroll
      for (int r = 0; r < 4; r++) {
        float p = mrow[r * Ssz] ? 0.f : __expf(sacc[r] * scale);
        unsigned short pb = f2bf(p);
        prt[r] += bf2f(pb);  // denom from rounded p: systematic rounding cancels
        Ps[wave * 16 + quad * 4 + r][col] = pb;
      }
    }
#pragma unroll
    for (int r = 0; r < 4; r++) {
      float v = prt[r];
      v += __shfl_xor(v, 1);
      v += __shfl_xor(v, 2);
      v += __shfl_xor(v, 4);
      v += __shfl_xor(v, 8);
      dsum[r] += v;
    }
#pragma unroll
    for (int kk = 0; kk < 2; kk++) {
      bf8 pf = *(const bf8*)&Ps[wave * 16 + lrow][kk * 32 + quad * 8];
#pragma unroll
      for (int j = 0; j < 4; j++) {
        bf8 vf = *(const bf8*)&Vts[j * 16 + lrow][kk * 32 + quad * 8];
        oacc[j] = __builtin_amdgcn_mfma_f32_16x16x32_bf16(pf, vf, oacc[j], 0, 0, 0);
      }
    }
  }

#pragma unroll
  for (int j = 0; j < 4; j++)
#pragma unroll
    for (int r = 0; r < 4; r++)
      O[(size_t)(b * Tt + trow + r) * Ee + h * 64 + j * 16 + lrow] =
          f2bf(oacc[j][r] / dsum[r]);
}

// ---------------- launcher ----------------
extern "C" void kernel_launch(void* const* d_in, const int* in_sizes, int n_in,
                              void* d_out, int out_size, void* d_ws, size_t ws_size,
                              hipStream_t stream) {
  const float* x    = (const float*)d_in[0];
  const float* ctx  = (const float*)d_in[1];
  const int*   mask = (const int*)d_in[2];
  const float* w_in = (const float*)d_in[3];
  const float* b_in = (const float*)d_in[4];
  const float* wq   = (const float*)d_in[5];
  const float* bq   = (const float*)d_in[6];
  const float* wk   = (const float*)d_in[7];
  const float* bk   = (const float*)d_in[8];
  const float* wv   = (const float*)d_in[9];
  const float* bv   = (const float*)d_in[10];
  const float* wo   = (const float*)d_in[11];
  const float* bo   = (const float*)d_in[12];

  unsigned short* ws = (unsigned short*)d_ws;
  unsigned short* xb   = ws;                  // x bf16        [8192,256]
  unsigned short* cb   = xb + 2097152;        // context bf16  [8192,512]
  unsigned short* winb = cb + 4194304;        // w_in bf16     [512,256]
  unsigned short* wqb  = winb + 131072;       // wq bf16       [512,512]
  unsigned short* wkb  = wqb + 262144;        // wk
  unsigned short* wvb  = wkb + 262144;        // wv
  unsigned short* wob  = wvb + 262144;        // w_out bf16    [256,512]
  unsigned short* xeb  = wob + 131072;        // xe bf16 [8192,512]; reused as attn-out
  unsigned short* Qb   = xeb + 4194304;       // Q bf16 [8192,512]
  unsigned short* Kb   = Qb + 4194304;        // K bf16
  unsigned short* Vb   = Kb + 4194304;        // V bf16

  castk<<<2048, 256, 0, stream>>>(x, xb, 524288);
  castk<<<4096, 256, 0, stream>>>(ctx, cb, 1048576);
  castk<<<128, 256, 0, stream>>>(w_in, winb, 32768);
  castk<<<256, 256, 0, stream>>>(wq, wqb, 65536);
  castk<<<256, 256, 0, stream>>>(wk, wkb, 65536);
  castk<<<256, 256, 0, stream>>>(wv, wvb, 65536);
  castk<<<128, 256, 0, stream>>>(wo, wob, 32768);

  gemm_bt<true><<<dim3(64, 4), 256, 0, stream>>>(xb, winb, b_in, xeb, 8192, 512, 256);
  gemm_bt<true><<<dim3(64, 4), 256, 0, stream>>>(xeb, wqb, bq, Qb, 8192, 512, 512);
  gemm_bt<true><<<dim3(64, 4), 256, 0, stream>>>(cb, wkb, bk, Kb, 8192, 512, 512);
  gemm_bt<true><<<dim3(64, 4), 256, 0, stream>>>(cb, wvb, bv, Vb, 8192, 512, 512);

  attn<<<dim3(32, 8, 4), 256, 0, stream>>>(Qb, Kb, Vb, mask, xeb);

  gemm_bt<false><<<dim3(64, 2), 256, 0, stream>>>(xeb, wob, bo, (float*)d_out,
                                                  8192, 256, 512);
}

// Round 2
// 299.829 us; speedup vs baseline: 1.2605x; 1.2605x over previous
//
#include <hip/hip_runtime.h>
#include <cstdint>
#include <cstddef>

#define Bb 4
#define Tt 2048
#define Ssz 2048
#define Cc 256
#define Ee 512
#define Hh 8

typedef short bf8 __attribute__((ext_vector_type(8)));
typedef float f4 __attribute__((ext_vector_type(4)));

__device__ __forceinline__ unsigned short f2bf(float x) {
  unsigned int u = __float_as_uint(x);
  u += 0x7fffu + ((u >> 16) & 1u);
  return (unsigned short)(u >> 16);
}
__device__ __forceinline__ float bf2f(unsigned short h) {
  return __uint_as_float(((unsigned int)h) << 16);
}

// ---------------- fp32 -> bf16 cast (vectorized) ----------------
__global__ __launch_bounds__(256) void castk(const float* __restrict__ s,
                                             unsigned short* __restrict__ d,
                                             int n4) {
  int i = blockIdx.x * 256 + threadIdx.x;
  if (i < n4) {
    float4 v = ((const float4*)s)[i];
    ushort4 o;
    o.x = f2bf(v.x);
    o.y = f2bf(v.y);
    o.z = f2bf(v.z);
    o.w = f2bf(v.w);
    ((ushort4*)d)[i] = o;
  }
}

// all 5 weight casts in one launch (segment sizes in float4 units)
__global__ __launch_bounds__(256) void castw(const float* __restrict__ w0, const float* __restrict__ w1,
                                             const float* __restrict__ w2, const float* __restrict__ w3,
                                             const float* __restrict__ w4,
                                             unsigned short* __restrict__ o0, unsigned short* __restrict__ o1,
                                             unsigned short* __restrict__ o2, unsigned short* __restrict__ o3,
                                             unsigned short* __restrict__ o4) {
  int i = blockIdx.x * 256 + threadIdx.x;  // 0..262143
  const float* s;
  unsigned short* d;
  int off;
  if (i < 32768)       { s = w0; d = o0; off = i; }
  else if (i < 98304)  { s = w1; d = o1; off = i - 32768; }
  else if (i < 163840) { s = w2; d = o2; off = i - 98304; }
  else if (i < 229376) { s = w3; d = o3; off = i - 163840; }
  else                 { s = w4; d = o4; off = i - 229376; }
  float4 v = ((const float4*)s)[off];
  ushort4 o;
  o.x = f2bf(v.x);
  o.y = f2bf(v.y);
  o.z = f2bf(v.z);
  o.w = f2bf(v.w);
  ((ushort4*)d)[off] = o;
}

// ---------------- mask -> bit-packed (1 bit per (t,s), 1=masked) ----------------
__global__ __launch_bounds__(256) void packmask(const int* __restrict__ m,
                                                unsigned int* __restrict__ p, int nwords) {
  int i = blockIdx.x * 256 + threadIdx.x;
  if (i >= nwords) return;
  const int4* src = (const int4*)m + (size_t)i * 8;
  unsigned int w = 0;
#pragma unroll
  for (int k = 0; k < 8; k++) {
    int4 v = src[k];
    w |= (unsigned int)(v.x != 0) << (k * 4);
    w |= (unsigned int)(v.y != 0) << (k * 4 + 1);
    w |= (unsigned int)(v.z != 0) << (k * 4 + 2);
    w |= (unsigned int)(v.w != 0) << (k * 4 + 3);
  }
  p[i] = w;
}

// ---------------- V [token][e] -> Vt [b][h][d][s] ----------------
__global__ __launch_bounds__(256) void vtrans(const unsigned short* __restrict__ V,
                                              unsigned short* __restrict__ Vt) {
  __shared__ unsigned short tile[64][72];
  const int tid = threadIdx.x;
  const int b = blockIdx.z, h = blockIdx.y, s0 = blockIdx.x * 64;
#pragma unroll
  for (int i = 0; i < 2; i++) {
    int id = tid + i * 256;
    int row = id >> 3, c = id & 7;
    *(bf8*)&tile[row][c * 8] =
        *(const bf8*)(V + (size_t)(b * Ssz + s0 + row) * Ee + h * 64 + c * 8);
  }
  __syncthreads();
#pragma unroll
  for (int i = 0; i < 2; i++) {
    int id = tid + i * 256;
    int d = id >> 3, c = id & 7;
    bf8 o;
#pragma unroll
    for (int k = 0; k < 8; k++) {
      int kk = (k + d) & 7;  // rotate gather order -> conflict-free banks
      o[kk] = (short)tile[c * 8 + kk][d];
    }
    *(bf8*)(Vt + (size_t)((b * Hh + h) * 64 + d) * Ssz + s0 + c * 8) = o;
  }
}

// ---------------- GEMM: C[M,N] = A[M,K] * Bt[N,K]^T + bias ----------------
// BM x 64 tile, BK=64, 256 threads, register-prefetch double buffer.
template <bool OUT_BF16, int BM>
__global__ __launch_bounds__(256) void gemm_bt(const unsigned short* __restrict__ A,
                                               const unsigned short* __restrict__ Bt,
                                               const float* __restrict__ bias,
                                               void* __restrict__ Cout,
                                               int M, int N, int K) {
  constexpr int NA = BM / 32;  // A bf8 slots per thread per k-tile
  constexpr int MI = BM / 64;  // row frags per wave
  __shared__ unsigned short As[BM][72];
  __shared__ unsigned short Bs[64][72];
  const int tid = threadIdx.x;
  const int wave = tid >> 6, lane = tid & 63;
  const int lrow = lane & 15, quad = lane >> 4;
  const int wm = wave * (BM / 4);
  const int m0 = blockIdx.x * BM, n0 = blockIdx.y * 64;
  const int arow = tid >> 3, ac = tid & 7;

  f4 acc[MI][4];
#pragma unroll
  for (int i = 0; i < MI; i++)
#pragma unroll
    for (int j = 0; j < 4; j++) {
      f4 z = {0.f, 0.f, 0.f, 0.f};
      acc[i][j] = z;
    }

  bf8 apre[NA], bpre[2];
#pragma unroll
  for (int i = 0; i < NA; i++)
    apre[i] = *(const bf8*)(A + (size_t)(m0 + arow + i * 32) * K + ac * 8);
#pragma unroll
  for (int i = 0; i < 2; i++)
    bpre[i] = *(const bf8*)(Bt + (size_t)(n0 + arow + i * 32) * K + ac * 8);

  const int nkt = K >> 6;
  for (int kt = 0; kt < nkt; ++kt) {
#pragma unroll
    for (int i = 0; i < NA; i++) *(bf8*)&As[arow + i * 32][ac * 8] = apre[i];
#pragma unroll
    for (int i = 0; i < 2; i++) *(bf8*)&Bs[arow + i * 32][ac * 8] = bpre[i];
    __syncthreads();
    if (kt + 1 < nkt) {
      int k0 = (kt + 1) << 6;
#pragma unroll
      for (int i = 0; i < NA; i++)
        apre[i] = *(const bf8*)(A + (size_t)(m0 + arow + i * 32) * K + k0 + ac * 8);
#pragma unroll
      for (int i = 0; i < 2; i++)
        bpre[i] = *(const bf8*)(Bt + (size_t)(n0 + arow + i * 32) * K + k0 + ac * 8);
    }
#pragma unroll
    for (int kk = 0; kk < 2; kk++) {
      bf8 af[MI], bff[4];
#pragma unroll
      for (int i = 0; i < MI; i++)
        af[i] = *(const bf8*)&As[wm + i * 16 + lrow][kk * 32 + quad * 8];
#pragma unroll
      for (int j = 0; j < 4; j++)
        bff[j] = *(const bf8*)&Bs[j * 16 + lrow][kk * 32 + quad * 8];
#pragma unroll
      for (int i = 0; i < MI; i++)
#pragma unroll
        for (int j = 0; j < 4; j++)
          acc[i][j] = __builtin_amdgcn_mfma_f32_16x16x32_bf16(af[i], bff[j],
                                                              acc[i][j], 0, 0, 0);
    }
    __syncthreads();
  }

#pragma unroll
  for (int j = 0; j < 4; j++) {
    int col = n0 + j * 16 + lrow;
    float bvv = bias ? bias[col] : 0.f;
#pragma unroll
    for (int i = 0; i < MI; i++) {
#pragma unroll
      for (int r = 0; r < 4; r++) {
        int row = m0 + wm + i * 16 + quad * 4 + r;
        float v = acc[i][j][r] + bvv;
        if (OUT_BF16)
          ((unsigned short*)Cout)[(size_t)row * N + col] = f2bf(v);
        else
          ((float*)Cout)[(size_t)row * N + col] = v;
      }
    }
  }
}

// ---------------- fused masked cross-attention ----------------
// grid (T/64, H, B). K/Vt register-prefetch pipeline, bit-packed mask from L2,
// P LDS round-trip is wave-local (no extra barrier).
__global__ __launch_bounds__(256) void attn(const unsigned short* __restrict__ Q,
                                            const unsigned short* __restrict__ K,
                                            const unsigned short* __restrict__ Vt,
                                            const unsigned int* __restrict__ mp,
                                            unsigned short* __restrict__ O) {
  __shared__ unsigned short Ks[64][72];
  __shared__ unsigned short Vts[64][72];
  __shared__ unsigned short Ps[64][72];  // Q staging, then P tiles
  const int tid = threadIdx.x;
  const int wave = tid >> 6, lane = tid & 63;
  const int lrow = lane & 15, quad = lane >> 4;
  const int b = blockIdx.z, h = blockIdx.y, t0 = blockIdx.x * 64;
  const float scale = 0.044194173824159216f;  // 512^-0.5
  const int arow = tid >> 3, ac = tid & 7;

  // stage Q tile through Ps space
#pragma unroll
  for (int i = 0; i < 2; i++) {
    int row = arow + i * 32;
    *(bf8*)&Ps[row][ac * 8] =
        *(const bf8*)(Q + (size_t)(b * Tt + t0 + row) * Ee + h * 64 + ac * 8);
  }
  __syncthreads();
  bf8 qf0 = *(const bf8*)&Ps[wave * 16 + lrow][quad * 8];
  bf8 qf1 = *(const bf8*)&Ps[wave * 16 + lrow][32 + quad * 8];

  f4 oacc[4];
#pragma unroll
  for (int j = 0; j < 4; j++) {
    f4 z = {0.f, 0.f, 0.f, 0.f};
    oacc[j] = z;
  }
  float dsum[4] = {0.f, 0.f, 0.f, 0.f};
  const int trow = t0 + wave * 16 + quad * 4;

  const unsigned short* Kbase = K + (size_t)b * Ssz * Ee + h * 64;
  const unsigned short* Vbase = Vt + (size_t)((b * Hh + h) * 64) * Ssz;
  const unsigned int* mbase = mp + (size_t)(b * Tt + trow) * 64;

  bf8 kreg[2], vreg[2];
#pragma unroll
  for (int i = 0; i < 2; i++) {
    int row = arow + i * 32;
    kreg[i] = *(const bf8*)(Kbase + (size_t)row * Ee + ac * 8);
    vreg[i] = *(const bf8*)(Vbase + (size_t)row * Ssz + ac * 8);
  }

  for (int s0 = 0; s0 < Ssz; s0 += 64) {
    __syncthreads();  // prior tile's LDS reads (and Q-frag reads) complete
#pragma unroll
    for (int i = 0; i < 2; i++) {
      int row = arow + i * 32;
      *(bf8*)&Ks[row][ac * 8] = kreg[i];
      *(bf8*)&Vts[row][ac * 8] = vreg[i];
    }
    __syncthreads();
    if (s0 + 64 < Ssz) {
#pragma unroll
      for (int i = 0; i < 2; i++) {
        int row = arow + i * 32;
        kreg[i] = *(const bf8*)(Kbase + (size_t)(s0 + 64 + row) * Ee + ac * 8);
        vreg[i] = *(const bf8*)(Vbase + (size_t)row * Ssz + s0 + 64 + ac * 8);
      }
    }
    uint2 mw[4];
#pragma unroll
    for (int r = 0; r < 4; r++)
      mw[r] = *(const uint2*)(mbase + (size_t)r * 64 + (s0 >> 5));

    float prt[4] = {0.f, 0.f, 0.f, 0.f};
#pragma unroll
    for (int j = 0; j < 4; j++) {
      f4 sacc = {0.f, 0.f, 0.f, 0.f};
      sacc = __builtin_amdgcn_mfma_f32_16x16x32_bf16(
          qf0, *(const bf8*)&Ks[j * 16 + lrow][quad * 8], sacc, 0, 0, 0);
      sacc = __builtin_amdgcn_mfma_f32_16x16x32_bf16(
          qf1, *(const bf8*)&Ks[j * 16 + lrow][32 + quad * 8], sacc, 0, 0, 0);
      int col = j * 16 + lrow;
      unsigned int bit = ((j & 1) << 4) + lrow;
#pragma unroll
      for (int r = 0; r < 4; r++) {
        unsigned int w = (j >> 1) ? mw[r].y : mw[r].x;
        float e = __expf(sacc[r] * scale);
        float p = ((w >> bit) & 1u) ? 0.f : e;
        unsigned short pb = f2bf(p);
        prt[r] += bf2f(pb);  // denom from rounded p: rounding cancels in the ratio
        Ps[wave * 16 + quad * 4 + r][col] = pb;
      }
    }
#pragma unroll
    for (int r = 0; r < 4; r++) {
      float v = prt[r];
      v += __shfl_xor(v, 1);
      v += __shfl_xor(v, 2);
      v += __shfl_xor(v, 4);
      v += __shfl_xor(v, 8);
      dsum[r] += v;
    }
#pragma unroll
    for (int kk = 0; kk < 2; kk++) {
      bf8 pf = *(const bf8*)&Ps[wave * 16 + lrow][kk * 32 + quad * 8];
#pragma unroll
      for (int j = 0; j < 4; j++) {
        bf8 vf = *(const bf8*)&Vts[j * 16 + lrow][kk * 32 + quad * 8];
        oacc[j] = __builtin_amdgcn_mfma_f32_16x16x32_bf16(pf, vf, oacc[j], 0, 0, 0);
      }
    }
  }

#pragma unroll
  for (int j = 0; j < 4; j++)
#pragma unroll
    for (int r = 0; r < 4; r++)
      O[(size_t)(b * Tt + trow + r) * Ee + h * 64 + j * 16 + lrow] =
          f2bf(oacc[j][r] / dsum[r]);
}

// ---------------- launcher ----------------
extern "C" void kernel_launch(void* const* d_in, const int* in_sizes, int n_in,
                              void* d_out, int out_size, void* d_ws, size_t ws_size,
                              hipStream_t stream) {
  const float* x    = (const float*)d_in[0];
  const float* ctx  = (const float*)d_in[1];
  const int*   mask = (const int*)d_in[2];
  const float* w_in = (const float*)d_in[3];
  const float* b_in = (const float*)d_in[4];
  const float* wq   = (const float*)d_in[5];
  const float* bq   = (const float*)d_in[6];
  const float* wk   = (const float*)d_in[7];
  const float* bk   = (const float*)d_in[8];
  const float* wv   = (const float*)d_in[9];
  const float* bv   = (const float*)d_in[10];
  const float* wo   = (const float*)d_in[11];
  const float* bo   = (const float*)d_in[12];

  unsigned short* ws = (unsigned short*)d_ws;
  unsigned short* xb   = ws;                  // x bf16 [8192,256]; later maskp
  unsigned short* cb   = xb + 2097152;        // ctx bf16 [8192,512]; later Vt
  unsigned short* winb = cb + 4194304;        // w_in bf16
  unsigned short* wqb  = winb + 131072;
  unsigned short* wkb  = wqb + 262144;
  unsigned short* wvb  = wkb + 262144;
  unsigned short* wob  = wvb + 262144;
  unsigned short* xeb  = wob + 131072;        // xe bf16; reused as attn-out
  unsigned short* Qb   = xeb + 4194304;
  unsigned short* Kb   = Qb + 4194304;
  unsigned short* Vb   = Kb + 4194304;
  unsigned int*  maskp = (unsigned int*)xb;   // aliases xb (dead after gemm #1)
  unsigned short* Vtb  = cb;                  // aliases cb (dead after V gemm)

  castk<<<2048, 256, 0, stream>>>(x, xb, 524288);
  castk<<<4096, 256, 0, stream>>>(ctx, cb, 1048576);
  castw<<<1024, 256, 0, stream>>>(w_in, wq, wk, wv, wo, winb, wqb, wkb, wvb, wob);

  gemm_bt<true, 128><<<dim3(64, 8), 256, 0, stream>>>(xb, winb, b_in, xeb, 8192, 512, 256);
  packmask<<<2048, 256, 0, stream>>>(mask, maskp, 524288);  // xb dead now
  gemm_bt<true, 128><<<dim3(64, 8), 256, 0, stream>>>(xeb, wqb, bq, Qb, 8192, 512, 512);
  gemm_bt<true, 128><<<dim3(64, 8), 256, 0, stream>>>(cb, wkb, bk, Kb, 8192, 512, 512);
  gemm_bt<true, 128><<<dim3(64, 8), 256, 0, stream>>>(cb, wvb, bv, Vb, 8192, 512, 512);
  vtrans<<<dim3(32, 8, 4), 256, 0, stream>>>(Vb, Vtb);  // cb dead now

  attn<<<dim3(32, 8, 4), 256, 0, stream>>>(Qb, Kb, Vtb, maskp, xeb);

  gemm_bt<false, 64><<<dim3(128, 4), 256, 0, stream>>>(xeb, wob, bo, d_out, 8192, 256, 512);
}

// Round 4
// 275.210 us; speedup vs baseline: 1.3733x; 1.0895x over previous
//
#include <hip/hip_runtime.h>
#include <cstdint>
#include <cstddef>

#define Bb 4
#define Tt 2048
#define Ssz 2048
#define Cc 256
#define Ee 512
#define Hh 8
#define LDK 1024

typedef short bf8 __attribute__((ext_vector_type(8)));
typedef float f4 __attribute__((ext_vector_type(4)));

__device__ __forceinline__ unsigned short f2bf(float x) {
  unsigned int u = __float_as_uint(x);
  u += 0x7fffu + ((u >> 16) & 1u);
  return (unsigned short)(u >> 16);
}

// ---------------- fp32 -> bf16 cast ----------------
__global__ __launch_bounds__(256) void castk(const float* __restrict__ s,
                                             unsigned short* __restrict__ d,
                                             int n4) {
  int i = blockIdx.x * 256 + threadIdx.x;
  if (i < n4) {
    float4 v = ((const float4*)s)[i];
    ushort4 o;
    o.x = f2bf(v.x);
    o.y = f2bf(v.y);
    o.z = f2bf(v.z);
    o.w = f2bf(v.w);
    ((ushort4*)d)[i] = o;
  }
}

// wq (pre-scaled by SCALE*log2e), wk, wv, wo in one launch
__global__ __launch_bounds__(256) void castw(const float* __restrict__ w0, const float* __restrict__ w1,
                                             const float* __restrict__ w2, const float* __restrict__ w3,
                                             unsigned short* __restrict__ o0, unsigned short* __restrict__ o1,
                                             unsigned short* __restrict__ o2, unsigned short* __restrict__ o3,
                                             float qsc) {
  int i = blockIdx.x * 256 + threadIdx.x;  // 0..229375
  const float* s;
  unsigned short* d;
  int off;
  float sc = 1.f;
  if (i < 65536)       { s = w0; d = o0; off = i; sc = qsc; }
  else if (i < 131072) { s = w1; d = o1; off = i - 65536; }
  else if (i < 196608) { s = w2; d = o2; off = i - 131072; }
  else                 { s = w3; d = o3; off = i - 196608; }
  float4 v = ((const float4*)s)[off];
  ushort4 o;
  o.x = f2bf(v.x * sc);
  o.y = f2bf(v.y * sc);
  o.z = f2bf(v.z * sc);
  o.w = f2bf(v.w * sc);
  ((ushort4*)d)[off] = o;
}

// w_in [512,256] fp32 -> transposed bf16 [256,512]
__global__ __launch_bounds__(256) void tcast(const float* __restrict__ w,
                                             unsigned short* __restrict__ o) {
  __shared__ float t[64][65];
  const int c0 = blockIdx.x * 64, e0 = blockIdx.y * 64;
  const int tid = threadIdx.x;
  const int row = tid >> 2, c4 = (tid & 3) * 4;
#pragma unroll
  for (int l = 0; l < 4; l++) {
    float4 v = *(const float4*)(w + (size_t)(e0 + row) * Cc + c0 + c4 + l * 16);
    t[row][c4 + l * 16 + 0] = v.x;
    t[row][c4 + l * 16 + 1] = v.y;
    t[row][c4 + l * 16 + 2] = v.z;
    t[row][c4 + l * 16 + 3] = v.w;
  }
  __syncthreads();
#pragma unroll
  for (int l = 0; l < 2; l++) {
    int id = tid + l * 256;
    int c = id >> 3, ch = id & 7;
    bf8 ov;
#pragma unroll
    for (int k = 0; k < 8; k++) {
      int kk = (k + c) & 7;
      ov[kk] = (short)f2bf(t[ch * 8 + kk][c]);
    }
    *(bf8*)(o + (size_t)(c0 + c) * Ee + e0 + ch * 8) = ov;
  }
}

// bqin = (wq . b_in + bq) * qsc   (fp32, 512 outputs)
__global__ __launch_bounds__(256) void bqin_k(const float* __restrict__ wq,
                                              const float* __restrict__ b_in,
                                              const float* __restrict__ bq,
                                              float* __restrict__ out, float qsc) {
  int i = blockIdx.x * 256 + threadIdx.x;
  float s = 0.f;
  for (int e = 0; e < Ee; e += 4) {
    float4 w = *(const float4*)(wq + (size_t)i * Ee + e);
    float4 b = *(const float4*)(b_in + e);
    s += w.x * b.x + w.y * b.y + w.z * b.z + w.w * b.w;
  }
  out[i] = (s + bq[i]) * qsc;
}

// ---------------- mask -> bit-packed ----------------
__global__ __launch_bounds__(256) void packmask(const int* __restrict__ m,
                                                unsigned int* __restrict__ p, int nwords) {
  int i = blockIdx.x * 256 + threadIdx.x;
  if (i >= nwords) return;
  const int4* src = (const int4*)m + (size_t)i * 8;
  unsigned int w = 0;
#pragma unroll
  for (int k = 0; k < 8; k++) {
    int4 v = src[k];
    w |= (unsigned int)(v.x != 0) << (k * 4);
    w |= (unsigned int)(v.y != 0) << (k * 4 + 1);
    w |= (unsigned int)(v.z != 0) << (k * 4 + 2);
    w |= (unsigned int)(v.w != 0) << (k * 4 + 3);
  }
  p[i] = w;
}

// ---------------- V (strided, ld) -> Vt [b][h][d][s] ----------------
__global__ __launch_bounds__(256) void vtrans(const unsigned short* __restrict__ V, int ldv,
                                              unsigned short* __restrict__ Vt) {
  __shared__ unsigned short tile[64][72];
  const int tid = threadIdx.x;
  const int b = blockIdx.z, h = blockIdx.y, s0 = blockIdx.x * 64;
#pragma unroll
  for (int i = 0; i < 2; i++) {
    int id = tid + i * 256;
    int row = id >> 3, c = id & 7;
    *(bf8*)&tile[row][c * 8] =
        *(const bf8*)(V + (size_t)(b * Ssz + s0 + row) * ldv + h * 64 + c * 8);
  }
  __syncthreads();
#pragma unroll
  for (int i = 0; i < 2; i++) {
    int id = tid + i * 256;
    int d = id >> 3, c = id & 7;
    bf8 o;
#pragma unroll
    for (int k = 0; k < 8; k++) {
      int kk = (k + d) & 7;
      o[kk] = (short)tile[c * 8 + kk][d];
    }
    *(bf8*)(Vt + (size_t)((b * Hh + h) * 64 + d) * Ssz + s0 + c * 8) = o;
  }
}

// ---------------- GEMM: C[M,N] = A[M,K] * Bt[N,K]^T + bias ----------------
// BM x BN tile, BK=64, 256 threads (4 waves as WGM x WGN), register prefetch.
template <bool OUT_BF16, int BM, int BN, int WGM>
__global__ __launch_bounds__(256) void gemm_bt(const unsigned short* __restrict__ A,
                                               const unsigned short* __restrict__ Bt,
                                               const float* __restrict__ bias0,
                                               const float* __restrict__ bias1, int split,
                                               void* __restrict__ Cout,
                                               int M, int N, int K) {
  constexpr int WGN = 4 / WGM;
  constexpr int MI = BM / (WGM * 16);
  constexpr int NJ = BN / (WGN * 16);
  constexpr int NA = BM / 32;
  constexpr int NB = BN / 32;
  __shared__ unsigned short As[BM][72];
  __shared__ unsigned short Bs[BN][72];
  const int tid = threadIdx.x;
  const int wave = tid >> 6, lane = tid & 63;
  const int lrow = lane & 15, quad = lane >> 4;
  const int wm = (wave / WGN) * (BM / WGM);
  const int wn = (wave % WGN) * (BN / WGN);
  const int m0 = blockIdx.x * BM, n0 = blockIdx.y * BN;
  const int arow = tid >> 3, ac = tid & 7;

  f4 acc[MI][NJ];
#pragma unroll
  for (int i = 0; i < MI; i++)
#pragma unroll
    for (int j = 0; j < NJ; j++) {
      f4 z = {0.f, 0.f, 0.f, 0.f};
      acc[i][j] = z;
    }

  bf8 apre[NA], bpre[NB];
#pragma unroll
  for (int i = 0; i < NA; i++)
    apre[i] = *(const bf8*)(A + (size_t)(m0 + arow + i * 32) * K + ac * 8);
#pragma unroll
  for (int i = 0; i < NB; i++)
    bpre[i] = *(const bf8*)(Bt + (size_t)(n0 + arow + i * 32) * K + ac * 8);

  const int nkt = K >> 6;
  for (int kt = 0; kt < nkt; ++kt) {
#pragma unroll
    for (int i = 0; i < NA; i++) *(bf8*)&As[arow + i * 32][ac * 8] = apre[i];
#pragma unroll
    for (int i = 0; i < NB; i++) *(bf8*)&Bs[arow + i * 32][ac * 8] = bpre[i];
    __syncthreads();
    if (kt + 1 < nkt) {
      int k0 = (kt + 1) << 6;
#pragma unroll
      for (int i = 0; i < NA; i++)
        apre[i] = *(const bf8*)(A + (size_t)(m0 + arow + i * 32) * K + k0 + ac * 8);
#pragma unroll
      for (int i = 0; i < NB; i++)
        bpre[i] = *(const bf8*)(Bt + (size_t)(n0 + arow + i * 32) * K + k0 + ac * 8);
    }
#pragma unroll
    for (int kk = 0; kk < 2; kk++) {
      bf8 af[MI], bff[NJ];
#pragma unroll
      for (int i = 0; i < MI; i++)
        af[i] = *(const bf8*)&As[wm + i * 16 + lrow][kk * 32 + quad * 8];
#pragma unroll
      for (int j = 0; j < NJ; j++)
        bff[j] = *(const bf8*)&Bs[wn + j * 16 + lrow][kk * 32 + quad * 8];
#pragma unroll
      for (int i = 0; i < MI; i++)
#pragma unroll
        for (int j = 0; j < NJ; j++)
          acc[i][j] = __builtin_amdgcn_mfma_f32_16x16x32_bf16(af[i], bff[j],
                                                              acc[i][j], 0, 0, 0);
    }
    __syncthreads();
  }

#pragma unroll
  for (int j = 0; j < NJ; j++) {
    int col = n0 + wn + j * 16 + lrow;
    float bvv = 0.f;
    if (bias0) bvv = (col < split) ? bias0[col] : bias1[col - split];
#pragma unroll
    for (int i = 0; i < MI; i++) {
#pragma unroll
      for (int r = 0; r < 4; r++) {
        int row = m0 + wm + i * 16 + quad * 4 + r;
        float v = acc[i][j][r] + bvv;
        if (OUT_BF16)
          ((unsigned short*)Cout)[(size_t)row * N + col] = f2bf(v);
        else
          ((float*)Cout)[(size_t)row * N + col] = v;
      }
    }
  }
}

// ---------------- fused masked cross-attention ----------------
// 128 Q-rows x 64 S per block; wave = 32 Q-rows (2 m-frags) -> K/V frag reads
// amortized 2x. Q pre-scaled by SCALE*log2e -> p = exp2(s). Denominator via
// MFMA ones-column (same rounded P as numerator; lands in oacc lane layout).
__global__ __launch_bounds__(256) void attn(const unsigned short* __restrict__ Q,
                                            const unsigned short* __restrict__ K,
                                            const unsigned short* __restrict__ Vt,
                                            const unsigned int* __restrict__ mp,
                                            unsigned short* __restrict__ O) {
  __shared__ unsigned short Ks[64][72];
  __shared__ unsigned short Vts[64][72];
  __shared__ unsigned short Ps[128][72];  // Q staging, then P tiles
  const int tid = threadIdx.x;
  const int wave = tid >> 6, lane = tid & 63;
  const int lrow = lane & 15, quad = lane >> 4;
  const int b = blockIdx.z, h = blockIdx.y, t0 = blockIdx.x * 128;
  const int arow = tid >> 3, ac = tid & 7;
  const int wm = wave * 32;

  // stage Q tile 128x64 through Ps
#pragma unroll
  for (int i = 0; i < 4; i++) {
    int row = arow + i * 32;
    *(bf8*)&Ps[row][ac * 8] =
        *(const bf8*)(Q + (size_t)(b * Tt + t0 + row) * Ee + h * 64 + ac * 8);
  }
  __syncthreads();
  bf8 qf[2][2];
#pragma unroll
  for (int mi = 0; mi < 2; mi++) {
    qf[mi][0] = *(const bf8*)&Ps[wm + mi * 16 + lrow][quad * 8];
    qf[mi][1] = *(const bf8*)&Ps[wm + mi * 16 + lrow][32 + quad * 8];
  }

  f4 oacc[2][4];
  f4 dacc[2];
#pragma unroll
  for (int mi = 0; mi < 2; mi++) {
    f4 z = {0.f, 0.f, 0.f, 0.f};
    dacc[mi] = z;
#pragma unroll
    for (int j = 0; j < 4; j++) oacc[mi][j] = z;
  }
  bf8 ones;
#pragma unroll
  for (int k = 0; k < 8; k++) ones[k] = (short)0x3F80;  // bf16 1.0

  const unsigned short* Kbase = K + (size_t)b * Ssz * LDK + h * 64;
  const unsigned short* Vbase = Vt + (size_t)((b * Hh + h) * 64) * Ssz;

  bf8 kreg[2], vreg[2];
#pragma unroll
  for (int i = 0; i < 2; i++) {
    int row = arow + i * 32;
    kreg[i] = *(const bf8*)(Kbase + (size_t)row * LDK + ac * 8);
    vreg[i] = *(const bf8*)(Vbase + (size_t)row * Ssz + ac * 8);
  }

  for (int s0 = 0; s0 < Ssz; s0 += 64) {
    __syncthreads();
#pragma unroll
    for (int i = 0; i < 2; i++) {
      int row = arow + i * 32;
      *(bf8*)&Ks[row][ac * 8] = kreg[i];
      *(bf8*)&Vts[row][ac * 8] = vreg[i];
    }
    __syncthreads();
    if (s0 + 64 < Ssz) {
#pragma unroll
      for (int i = 0; i < 2; i++) {
        int row = arow + i * 32;
        kreg[i] = *(const bf8*)(Kbase + (size_t)(s0 + 64 + row) * LDK + ac * 8);
        vreg[i] = *(const bf8*)(Vbase + (size_t)row * Ssz + s0 + 64 + ac * 8);
      }
    }
    uint2 mw[2][4];
#pragma unroll
    for (int mi = 0; mi < 2; mi++)
#pragma unroll
      for (int r = 0; r < 4; r++)
        mw[mi][r] = *(const uint2*)(mp + (size_t)(b * Tt + t0 + wm + mi * 16 + quad * 4 + r) * 64 +
                                    (s0 >> 5));

#pragma unroll
    for (int j = 0; j < 4; j++) {
      bf8 kf0 = *(const bf8*)&Ks[j * 16 + lrow][quad * 8];
      bf8 kf1 = *(const bf8*)&Ks[j * 16 + lrow][32 + quad * 8];
      f4 s[2];
      f4 z = {0.f, 0.f, 0.f, 0.f};
      s[0] = z; s[1] = z;
      s[0] = __builtin_amdgcn_mfma_f32_16x16x32_bf16(qf[0][0], kf0, s[0], 0, 0, 0);
      s[0] = __builtin_amdgcn_mfma_f32_16x16x32_bf16(qf[0][1], kf1, s[0], 0, 0, 0);
      s[1] = __builtin_amdgcn_mfma_f32_16x16x32_bf16(qf[1][0], kf0, s[1], 0, 0, 0);
      s[1] = __builtin_amdgcn_mfma_f32_16x16x32_bf16(qf[1][1], kf1, s[1], 0, 0, 0);
      const int col = j * 16 + lrow;
      const unsigned int bit = ((j & 1) << 4) + lrow;
#pragma unroll
      for (int mi = 0; mi < 2; mi++) {
#pragma unroll
        for (int r = 0; r < 4; r++) {
          unsigned int w = (j >> 1) ? mw[mi][r].y : mw[mi][r].x;
          float e = __builtin_amdgcn_exp2f(s[mi][r]);
          float p = ((w >> bit) & 1u) ? 0.f : e;
          // truncation pack: systematic part cancels in numerator/denominator ratio
          Ps[wm + mi * 16 + quad * 4 + r][col] =
              (unsigned short)(__float_as_uint(p) >> 16);
        }
      }
    }
#pragma unroll
    for (int kk = 0; kk < 2; kk++) {
      bf8 pf[2];
#pragma unroll
      for (int mi = 0; mi < 2; mi++) {
        pf[mi] = *(const bf8*)&Ps[wm + mi * 16 + lrow][kk * 32 + quad * 8];
        dacc[mi] = __builtin_amdgcn_mfma_f32_16x16x32_bf16(pf[mi], ones, dacc[mi], 0, 0, 0);
      }
#pragma unroll
      for (int j = 0; j < 4; j++) {
        bf8 vf = *(const bf8*)&Vts[j * 16 + lrow][kk * 32 + quad * 8];
#pragma unroll
        for (int mi = 0; mi < 2; mi++)
          oacc[mi][j] = __builtin_amdgcn_mfma_f32_16x16x32_bf16(pf[mi], vf, oacc[mi][j], 0, 0, 0);
      }
    }
  }

#pragma unroll
  for (int mi = 0; mi < 2; mi++) {
#pragma unroll
    for (int r = 0; r < 4; r++) {
      float inv = 1.0f / dacc[mi][r];
      int row = b * Tt + t0 + wm + mi * 16 + quad * 4 + r;
#pragma unroll
      for (int j = 0; j < 4; j++)
        O[(size_t)row * Ee + h * 64 + j * 16 + lrow] = f2bf(oacc[mi][j][r] * inv);
    }
  }
}

// ---------------- launcher ----------------
extern "C" void kernel_launch(void* const* d_in, const int* in_sizes, int n_in,
                              void* d_out, int out_size, void* d_ws, size_t ws_size,
                              hipStream_t stream) {
  const float* x    = (const float*)d_in[0];
  const float* ctx  = (const float*)d_in[1];
  const int*   mask = (const int*)d_in[2];
  const float* w_in = (const float*)d_in[3];
  const float* b_in = (const float*)d_in[4];
  const float* wq   = (const float*)d_in[5];
  const float* bq   = (const float*)d_in[6];
  const float* wk   = (const float*)d_in[7];
  const float* bk   = (const float*)d_in[8];
  const float* wv   = (const float*)d_in[9];
  const float* bv   = (const float*)d_in[10];
  const float* wo   = (const float*)d_in[11];
  const float* bo   = (const float*)d_in[12];

  const float qsc = 0.04419417382415922f * 1.4426950408889634f;  // E^-0.5 * log2(e)

  unsigned short* ws = (unsigned short*)d_ws;
  unsigned short* xb   = ws;                    // x bf16 [8192,256]; later maskp
  unsigned short* cb   = ws + 2097152;          // ctx bf16 [8192,512]; later Vt
  unsigned short* wqb  = ws + 6291456;          // wq bf16 (pre-scaled) [512,512]
  unsigned short* wkb  = ws + 6553600;          // wk bf16 [512,512]
  unsigned short* wvb  = ws + 6815744;          // wv bf16 (contiguous after wk!)
  unsigned short* wob  = ws + 7077888;          // w_out bf16 [256,512]
  unsigned short* Qb   = ws + 7208960;          // Q bf16 [8192,512]
  unsigned short* KVb  = ws + 11403264;         // [8192,1024] K||V interleaved rows
  unsigned short* Ob   = ws + 19791872;         // attn out bf16 [8192,512]
  unsigned short* wqin = Ob;                    // fused W (live before attn) [512,256]
  unsigned short* winT = Ob + 131072;           // w_in^T bf16 [256,512]
  float*          bqinb = (float*)(Ob + 262144);  // fused Q bias fp32 [512]
  unsigned int*   maskp = (unsigned int*)xb;    // bit mask (after qgemm)
  unsigned short* Vtb  = cb;                    // V^T (after kvgemm)

  castk<<<2048, 256, 0, stream>>>(x, xb, 524288);
  castk<<<4096, 256, 0, stream>>>(ctx, cb, 1048576);
  castw<<<896, 256, 0, stream>>>(wq, wk, wv, wo, wqb, wkb, wvb, wob, qsc);
  tcast<<<dim3(4, 8), 256, 0, stream>>>(w_in, winT);
  bqin_k<<<2, 256, 0, stream>>>(wq, b_in, bq, bqinb, qsc);

  // Wqin[512,256] = wqb . w_in  (tiny weight GEMM)
  gemm_bt<true, 64, 64, 2><<<dim3(8, 4), 256, 0, stream>>>(
      wqb, winT, nullptr, nullptr, 256, wqin, 512, 256, 512);
  // Q[8192,512] = x . Wqin^T + bqin
  gemm_bt<true, 128, 64, 2><<<dim3(64, 8), 256, 0, stream>>>(
      xb, wqin, bqinb, nullptr, 512, Qb, 8192, 512, 256);
  packmask<<<2048, 256, 0, stream>>>(mask, maskp, 524288);  // xb dead now
  // KV[8192,1024] = ctx . [wk;wv]^T + [bk;bv]
  gemm_bt<true, 128, 128, 2><<<dim3(64, 8), 256, 0, stream>>>(
      cb, wkb, bk, bv, 512, KVb, 8192, 1024, 512);
  vtrans<<<dim3(32, 8, 4), 256, 0, stream>>>(KVb + 512, LDK, Vtb);  // cb dead now

  attn<<<dim3(16, 8, 4), 256, 0, stream>>>(Qb, KVb, Vtb, maskp, Ob);

  gemm_bt<false, 64, 64, 2><<<dim3(128, 4), 256, 0, stream>>>(
      Ob, wob, bo, nullptr, 256, d_out, 8192, 256, 512);
}

// Round 5
// 252.642 us; speedup vs baseline: 1.4960x; 1.0893x over previous
//
#include <hip/hip_runtime.h>
#include <cstdint>
#include <cstddef>

#define Bb 4
#define Tt 2048
#define Ssz 2048
#define Cc 256
#define Ee 512
#define Hh 8
#define LDK 1024

typedef short bf8 __attribute__((ext_vector_type(8)));
typedef float f4 __attribute__((ext_vector_type(4)));

__device__ __forceinline__ unsigned short f2bf(float x) {
  unsigned int u = __float_as_uint(x);
  u += 0x7fffu + ((u >> 16) & 1u);
  return (unsigned short)(u >> 16);
}

// ---------------- GEMM core: C[M,N] = A[M,K]*Bt[N,K]^T + bias ----------------
template <bool OUT_BF16, int BM, int BN, int WGM>
__device__ __forceinline__ void gemm_core(unsigned short (*As)[72],
                                          unsigned short (*Bs)[72],
                                          const unsigned short* __restrict__ A,
                                          const unsigned short* __restrict__ Bt,
                                          const float* __restrict__ bias0,
                                          const float* __restrict__ bias1, int split,
                                          void* __restrict__ Cout,
                                          int M, int N, int K, int m0, int n0) {
  constexpr int WGN = 4 / WGM;
  constexpr int MI = BM / (WGM * 16);
  constexpr int NJ = BN / (WGN * 16);
  constexpr int NA = BM / 32;
  constexpr int NB = BN / 32;
  const int tid = threadIdx.x;
  const int wave = tid >> 6, lane = tid & 63;
  const int lrow = lane & 15, quad = lane >> 4;
  const int wm = (wave / WGN) * (BM / WGM);
  const int wn = (wave % WGN) * (BN / WGN);
  const int arow = tid >> 3, ac = tid & 7;

  f4 acc[MI][NJ];
#pragma unroll
  for (int i = 0; i < MI; i++)
#pragma unroll
    for (int j = 0; j < NJ; j++) {
      f4 z = {0.f, 0.f, 0.f, 0.f};
      acc[i][j] = z;
    }

  bf8 apre[NA], bpre[NB];
#pragma unroll
  for (int i = 0; i < NA; i++)
    apre[i] = *(const bf8*)(A + (size_t)(m0 + arow + i * 32) * K + ac * 8);
#pragma unroll
  for (int i = 0; i < NB; i++)
    bpre[i] = *(const bf8*)(Bt + (size_t)(n0 + arow + i * 32) * K + ac * 8);

  const int nkt = K >> 6;
  for (int kt = 0; kt < nkt; ++kt) {
#pragma unroll
    for (int i = 0; i < NA; i++) *(bf8*)&As[arow + i * 32][ac * 8] = apre[i];
#pragma unroll
    for (int i = 0; i < NB; i++) *(bf8*)&Bs[arow + i * 32][ac * 8] = bpre[i];
    __syncthreads();
    if (kt + 1 < nkt) {
      int k0 = (kt + 1) << 6;
#pragma unroll
      for (int i = 0; i < NA; i++)
        apre[i] = *(const bf8*)(A + (size_t)(m0 + arow + i * 32) * K + k0 + ac * 8);
#pragma unroll
      for (int i = 0; i < NB; i++)
        bpre[i] = *(const bf8*)(Bt + (size_t)(n0 + arow + i * 32) * K + k0 + ac * 8);
    }
#pragma unroll
    for (int kk = 0; kk < 2; kk++) {
      bf8 af[MI], bff[NJ];
#pragma unroll
      for (int i = 0; i < MI; i++)
        af[i] = *(const bf8*)&As[wm + i * 16 + lrow][kk * 32 + quad * 8];
#pragma unroll
      for (int j = 0; j < NJ; j++)
        bff[j] = *(const bf8*)&Bs[wn + j * 16 + lrow][kk * 32 + quad * 8];
#pragma unroll
      for (int i = 0; i < MI; i++)
#pragma unroll
        for (int j = 0; j < NJ; j++)
          acc[i][j] = __builtin_amdgcn_mfma_f32_16x16x32_bf16(af[i], bff[j],
                                                              acc[i][j], 0, 0, 0);
    }
    __syncthreads();
  }

#pragma unroll
  for (int j = 0; j < NJ; j++) {
    int col = n0 + wn + j * 16 + lrow;
    float bvv = 0.f;
    if (bias0) bvv = (col < split) ? bias0[col] : bias1[col - split];
#pragma unroll
    for (int i = 0; i < MI; i++) {
#pragma unroll
      for (int r = 0; r < 4; r++) {
        int row = m0 + wm + i * 16 + quad * 4 + r;
        float v = acc[i][j][r] + bvv;
        if (OUT_BF16)
          ((unsigned short*)Cout)[(size_t)row * N + col] = f2bf(v);
        else
          ((float*)Cout)[(size_t)row * N + col] = v;
      }
    }
  }
}

template <bool OUT_BF16, int BM, int BN, int WGM>
__global__ __launch_bounds__(256) void gemm_bt(const unsigned short* __restrict__ A,
                                               const unsigned short* __restrict__ Bt,
                                               const float* __restrict__ bias0,
                                               const float* __restrict__ bias1, int split,
                                               void* __restrict__ Cout,
                                               int M, int N, int K) {
  __shared__ unsigned short As[BM][72];
  __shared__ unsigned short Bs[BN][72];
  gemm_core<OUT_BF16, BM, BN, WGM>(As, Bs, A, Bt, bias0, bias1, split, Cout, M, N, K,
                                   blockIdx.x * BM, blockIdx.y * BN);
}

// ---------------- prep: all casts + wqin GEMM + bqin, one launch ----------------
// blocks [0,2048): x cast; [2048,6144): ctx cast; [6144,6784): wk/wv/wo cast;
// [6784,6816): wqin = (qsc*wq).w_in  64x64 tiles; [6816,6832): bqin reduce.
__global__ __launch_bounds__(256) void prep(const float* __restrict__ x,
                                            const float* __restrict__ ctx,
                                            const float* __restrict__ w_in,
                                            const float* __restrict__ b_in,
                                            const float* __restrict__ wq,
                                            const float* __restrict__ bq,
                                            const float* __restrict__ wk,
                                            const float* __restrict__ wv,
                                            const float* __restrict__ wo,
                                            unsigned short* __restrict__ xb,
                                            unsigned short* __restrict__ cb,
                                            unsigned short* __restrict__ wkvb,
                                            unsigned short* __restrict__ wob,
                                            unsigned short* __restrict__ wqin,
                                            float* __restrict__ bqinb, float qsc) {
  __shared__ unsigned short sh[128][72];
  const int bid = blockIdx.x, tid = threadIdx.x;
  if (bid < 6144) {
    const float* s;
    unsigned short* d;
    int i;
    if (bid < 2048) { s = x; d = xb; i = bid * 256 + tid; }
    else            { s = ctx; d = cb; i = (bid - 2048) * 256 + tid; }
    float4 v = ((const float4*)s)[i];
    ushort4 o;
    o.x = f2bf(v.x); o.y = f2bf(v.y); o.z = f2bf(v.z); o.w = f2bf(v.w);
    ((ushort4*)d)[i] = o;
  } else if (bid < 6784) {
    int i = (bid - 6144) * 256 + tid;  // 0..163839
    const float* s;
    unsigned short* d;
    int off;
    if (i < 131072)      { s = wk; d = wkvb; off = i; }   // wk then wv contiguous
    else                 { s = wo; d = wob; off = i - 131072; }
    if (i >= 65536 && i < 131072) { s = wv; off = i - 65536; d = wkvb + 262144; }
    float4 v = ((const float4*)s)[off];
    ushort4 o;
    o.x = f2bf(v.x); o.y = f2bf(v.y); o.z = f2bf(v.z); o.w = f2bf(v.w);
    ((ushort4*)d)[off] = o;
  } else if (bid < 6816) {
    // wqin[512,256] = (qsc*wq)[512,512] . w_in[512,256], bf16 MFMA with
    // on-the-fly fp32->bf16 staging. BM=BN=64, K=512.
    const int idx = bid - 6784;
    const int m0 = (idx & 7) * 64, n0 = (idx >> 3) * 64;
    unsigned short (*As)[72] = (unsigned short (*)[72]) & sh[0][0];
    unsigned short (*Bs)[72] = (unsigned short (*)[72]) & sh[64][0];
    const int wave = tid >> 6, lane = tid & 63;
    const int lrow = lane & 15, quad = lane >> 4;
    const int wm = (wave >> 1) * 32, wn = (wave & 1) * 32;
    const int arow = tid >> 3, ac = tid & 7;
    f4 acc[2][2];
#pragma unroll
    for (int i = 0; i < 2; i++)
#pragma unroll
      for (int j = 0; j < 2; j++) {
        f4 z = {0.f, 0.f, 0.f, 0.f};
        acc[i][j] = z;
      }
    for (int kt = 0; kt < 8; kt++) {
#pragma unroll
      for (int i = 0; i < 2; i++) {
        int row = arow + i * 32;
        const float* src = wq + (size_t)(m0 + row) * Ee + kt * 64 + ac * 8;
        float4 v0 = *(const float4*)src, v1 = *(const float4*)(src + 4);
        bf8 av;
        av[0] = (short)f2bf(v0.x * qsc); av[1] = (short)f2bf(v0.y * qsc);
        av[2] = (short)f2bf(v0.z * qsc); av[3] = (short)f2bf(v0.w * qsc);
        av[4] = (short)f2bf(v1.x * qsc); av[5] = (short)f2bf(v1.y * qsc);
        av[6] = (short)f2bf(v1.z * qsc); av[7] = (short)f2bf(v1.w * qsc);
        *(bf8*)&As[row][ac * 8] = av;
        int c = n0 + row;
        bf8 bv;
#pragma unroll
        for (int k = 0; k < 8; k++)
          bv[k] = (short)f2bf(w_in[(size_t)(kt * 64 + ac * 8 + k) * Cc + c]);
        *(bf8*)&Bs[row][ac * 8] = bv;
      }
      __syncthreads();
#pragma unroll
      for (int kk = 0; kk < 2; kk++) {
        bf8 af[2], bff[2];
#pragma unroll
        for (int i = 0; i < 2; i++) af[i] = *(const bf8*)&As[wm + i * 16 + lrow][kk * 32 + quad * 8];
#pragma unroll
        for (int j = 0; j < 2; j++) bff[j] = *(const bf8*)&Bs[wn + j * 16 + lrow][kk * 32 + quad * 8];
#pragma unroll
        for (int i = 0; i < 2; i++)
#pragma unroll
          for (int j = 0; j < 2; j++)
            acc[i][j] = __builtin_amdgcn_mfma_f32_16x16x32_bf16(af[i], bff[j], acc[i][j], 0, 0, 0);
      }
      __syncthreads();
    }
#pragma unroll
    for (int j = 0; j < 2; j++)
#pragma unroll
      for (int i = 0; i < 2; i++)
#pragma unroll
        for (int r = 0; r < 4; r++)
          wqin[(size_t)(m0 + wm + i * 16 + quad * 4 + r) * Cc + n0 + wn + j * 16 + lrow] =
              f2bf(acc[i][j][r]);
  } else {
    // bqin[o] = (wq[o,:].b_in + bq[o]) * qsc ; 8 lanes per output
    const int o = (bid - 6816) * 32 + (tid >> 3);
    const int k0 = (tid & 7) * 64;
    float s = 0.f;
#pragma unroll
    for (int i = 0; i < 16; i++) {
      float4 w = *(const float4*)(wq + (size_t)o * Ee + k0 + i * 4);
      float4 bb = *(const float4*)(b_in + k0 + i * 4);
      s += w.x * bb.x + w.y * bb.y + w.z * bb.z + w.w * bb.w;
    }
    s += __shfl_xor(s, 1);
    s += __shfl_xor(s, 2);
    s += __shfl_xor(s, 4);
    if ((tid & 7) == 0) bqinb[o] = (s + bq[o]) * qsc;
  }
}

// ---------------- KV GEMM + packmask, one dispatch ----------------
// blocks [0,512): KV[8192,1024] = cb . [wk;wv]^T ; [512,2560): mask bit-pack.
__global__ __launch_bounds__(256) void kvpack(const unsigned short* __restrict__ cb,
                                              const unsigned short* __restrict__ wkv,
                                              const float* __restrict__ bk,
                                              const float* __restrict__ bv,
                                              unsigned short* __restrict__ KVout,
                                              const int* __restrict__ mask,
                                              unsigned int* __restrict__ mp) {
  __shared__ unsigned short As[128][72];
  __shared__ unsigned short Bs[128][72];
  const int bid = blockIdx.x;
  if (bid < 512) {
    gemm_core<true, 128, 128, 2>(As, Bs, cb, wkv, bk, bv, 512, KVout, 8192, 1024, 512,
                                 (bid & 63) * 128, (bid >> 6) * 128);
  } else {
    int i = (bid - 512) * 256 + threadIdx.x;  // 0..524287
    const int4* src = (const int4*)mask + (size_t)i * 8;
    unsigned int w = 0;
#pragma unroll
    for (int k = 0; k < 8; k++) {
      int4 v = src[k];
      w |= (unsigned int)(v.x != 0) << (k * 4);
      w |= (unsigned int)(v.y != 0) << (k * 4 + 1);
      w |= (unsigned int)(v.z != 0) << (k * 4 + 2);
      w |= (unsigned int)(v.w != 0) << (k * 4 + 3);
    }
    mp[i] = w;
  }
}

// ---------------- V (strided) -> Vt [b][h][d][s] ----------------
__global__ __launch_bounds__(256) void vtrans(const unsigned short* __restrict__ V, int ldv,
                                              unsigned short* __restrict__ Vt) {
  __shared__ unsigned short tile[64][72];
  const int tid = threadIdx.x;
  const int b = blockIdx.z, h = blockIdx.y, s0 = blockIdx.x * 64;
#pragma unroll
  for (int i = 0; i < 2; i++) {
    int id = tid + i * 256;
    int row = id >> 3, c = id & 7;
    *(bf8*)&tile[row][c * 8] =
        *(const bf8*)(V + (size_t)(b * Ssz + s0 + row) * ldv + h * 64 + c * 8);
  }
  __syncthreads();
#pragma unroll
  for (int i = 0; i < 2; i++) {
    int id = tid + i * 256;
    int d = id >> 3, c = id & 7;
    bf8 o;
#pragma unroll
    for (int k = 0; k < 8; k++) {
      int kk = (k + d) & 7;
      o[kk] = (short)tile[c * 8 + kk][d];
    }
    *(bf8*)(Vt + (size_t)((b * Hh + h) * 64 + d) * Ssz + s0 + c * 8) = o;
  }
}

// ---------------- fused masked cross-attention (S^T formulation) ----------------
// Per block: 128 t x full S. Computes S^T = K.Q^T so the P round-trip is
// vectorized: ds_write_b64 stores into t-major P[t][s], ds_read_b128 loads
// A-frags. Double-buffered K/V LDS -> 1 barrier per s-tile. Denominator via
// MFMA ones-column on the same rounded P (rounding cancels in the ratio).
__global__ __launch_bounds__(256) void attn(const unsigned short* __restrict__ Q,
                                            const unsigned short* __restrict__ K,
                                            const unsigned short* __restrict__ Vt,
                                            const unsigned int* __restrict__ mp,
                                            unsigned short* __restrict__ O) {
  __shared__ unsigned short Ks[2][64][72];
  __shared__ unsigned short Vts[2][64][72];
  __shared__ unsigned short Ps[128][72];  // Q staging, then P tiles (t-major)
  const int tid = threadIdx.x;
  const int wave = tid >> 6, lane = tid & 63;
  const int lrow = lane & 15, quad = lane >> 4;
  const int b = blockIdx.z, h = blockIdx.y, t0 = blockIdx.x * 128;
  const int arow = tid >> 3, ac = tid & 7;
  const int wm = wave * 32;

  // stage Q tile 128x64 through Ps
#pragma unroll
  for (int i = 0; i < 4; i++) {
    int row = arow + i * 32;
    *(bf8*)&Ps[row][ac * 8] =
        *(const bf8*)(Q + (size_t)(b * Tt + t0 + row) * Ee + h * 64 + ac * 8);
  }
  __syncthreads();
  bf8 qf[2][2];  // B-operand frags (n = t)
#pragma unroll
  for (int mi = 0; mi < 2; mi++) {
    qf[mi][0] = *(const bf8*)&Ps[wm + mi * 16 + lrow][quad * 8];
    qf[mi][1] = *(const bf8*)&Ps[wm + mi * 16 + lrow][32 + quad * 8];
  }

  f4 oacc[2][4];
  f4 dacc[2];
#pragma unroll
  for (int mi = 0; mi < 2; mi++) {
    f4 z = {0.f, 0.f, 0.f, 0.f};
    dacc[mi] = z;
#pragma unroll
    for (int j = 0; j < 4; j++) oacc[mi][j] = z;
  }
  bf8 ones;
#pragma unroll
  for (int k = 0; k < 8; k++) ones[k] = (short)0x3F80;  // bf16 1.0

  const unsigned short* Kbase = K + (size_t)b * Ssz * LDK + h * 64;
  const unsigned short* Vbase = Vt + (size_t)((b * Hh + h) * 64) * Ssz;
  const unsigned int* mrow0 = mp + (size_t)(b * Tt + t0 + wm + lrow) * 64;
  const unsigned int* mrow1 = mp + (size_t)(b * Tt + t0 + wm + 16 + lrow) * 64;

  bf8 kreg[2], vreg[2];
#pragma unroll
  for (int i = 0; i < 2; i++) {
    int row = arow + i * 32;
    kreg[i] = *(const bf8*)(Kbase + (size_t)row * LDK + ac * 8);
    vreg[i] = *(const bf8*)(Vbase + (size_t)row * Ssz + ac * 8);
  }

  int buf = 0;
  for (int s0 = 0; s0 < Ssz; s0 += 64) {
#pragma unroll
    for (int i = 0; i < 2; i++) {
      int row = arow + i * 32;
      *(bf8*)&Ks[buf][row][ac * 8] = kreg[i];
      *(bf8*)&Vts[buf][row][ac * 8] = vreg[i];
    }
    __syncthreads();
    if (s0 + 64 < Ssz) {
#pragma unroll
      for (int i = 0; i < 2; i++) {
        int row = arow + i * 32;
        kreg[i] = *(const bf8*)(Kbase + (size_t)(s0 + 64 + row) * LDK + ac * 8);
        vreg[i] = *(const bf8*)(Vbase + (size_t)row * Ssz + s0 + 64 + ac * 8);
      }
    }
    const uint2 mw0 = *(const uint2*)(mrow0 + (s0 >> 5));
    const uint2 mw1 = *(const uint2*)(mrow1 + (s0 >> 5));

    // scores: S^T tiles (rows = s, cols = t)
#pragma unroll
    for (int sf = 0; sf < 4; sf++) {
      bf8 kf0 = *(const bf8*)&Ks[buf][sf * 16 + lrow][quad * 8];
      bf8 kf1 = *(const bf8*)&Ks[buf][sf * 16 + lrow][32 + quad * 8];
      f4 sa[2];
      f4 z = {0.f, 0.f, 0.f, 0.f};
      sa[0] = z; sa[1] = z;
      sa[0] = __builtin_amdgcn_mfma_f32_16x16x32_bf16(kf0, qf[0][0], sa[0], 0, 0, 0);
      sa[0] = __builtin_amdgcn_mfma_f32_16x16x32_bf16(kf1, qf[0][1], sa[0], 0, 0, 0);
      sa[1] = __builtin_amdgcn_mfma_f32_16x16x32_bf16(kf0, qf[1][0], sa[1], 0, 0, 0);
      sa[1] = __builtin_amdgcn_mfma_f32_16x16x32_bf16(kf1, qf[1][1], sa[1], 0, 0, 0);
#pragma unroll
      for (int mi = 0; mi < 2; mi++) {
        const uint2 mw = mi ? mw1 : mw0;
        const unsigned int w = (sf >= 2) ? mw.y : mw.x;  // static per sf
        ushort4 pk;
#pragma unroll
        for (int r = 0; r < 4; r++) {
          const unsigned int bit = (sf & 1) * 16 + quad * 4 + r;
          float e = __builtin_amdgcn_exp2f(sa[mi][r]);
          float p = ((w >> bit) & 1u) ? 0.f : e;
          unsigned short pb = (unsigned short)(__float_as_uint(p) >> 16);
          if (r == 0) pk.x = pb;
          else if (r == 1) pk.y = pb;
          else if (r == 2) pk.z = pb;
          else pk.w = pb;
        }
        *(ushort4*)&Ps[wm + mi * 16 + lrow][sf * 16 + quad * 4] = pk;  // b64
      }
    }
    // PV + denominator
#pragma unroll
    for (int kk = 0; kk < 2; kk++) {
      bf8 pf[2];
#pragma unroll
      for (int mi = 0; mi < 2; mi++) {
        pf[mi] = *(const bf8*)&Ps[wm + mi * 16 + lrow][kk * 32 + quad * 8];  // b128
        dacc[mi] = __builtin_amdgcn_mfma_f32_16x16x32_bf16(pf[mi], ones, dacc[mi], 0, 0, 0);
      }
#pragma unroll
      for (int j = 0; j < 4; j++) {
        bf8 vf = *(const bf8*)&Vts[buf][j * 16 + lrow][kk * 32 + quad * 8];
#pragma unroll
        for (int mi = 0; mi < 2; mi++)
          oacc[mi][j] = __builtin_amdgcn_mfma_f32_16x16x32_bf16(pf[mi], vf, oacc[mi][j], 0, 0, 0);
      }
    }
    buf ^= 1;
  }

#pragma unroll
  for (int mi = 0; mi < 2; mi++) {
#pragma unroll
    for (int r = 0; r < 4; r++) {
      float inv = 1.0f / dacc[mi][r];
      int row = b * Tt + t0 + wm + mi * 16 + quad * 4 + r;
#pragma unroll
      for (int j = 0; j < 4; j++)
        O[(size_t)row * Ee + h * 64 + j * 16 + lrow] = f2bf(oacc[mi][j][r] * inv);
    }
  }
}

// ---------------- launcher ----------------
extern "C" void kernel_launch(void* const* d_in, const int* in_sizes, int n_in,
                              void* d_out, int out_size, void* d_ws, size_t ws_size,
                              hipStream_t stream) {
  const float* x    = (const float*)d_in[0];
  const float* ctx  = (const float*)d_in[1];
  const int*   mask = (const int*)d_in[2];
  const float* w_in = (const float*)d_in[3];
  const float* b_in = (const float*)d_in[4];
  const float* wq   = (const float*)d_in[5];
  const float* bq   = (const float*)d_in[6];
  const float* wk   = (const float*)d_in[7];
  const float* bk   = (const float*)d_in[8];
  const float* wv   = (const float*)d_in[9];
  const float* bv   = (const float*)d_in[10];
  const float* wo   = (const float*)d_in[11];
  const float* bo   = (const float*)d_in[12];

  const float qsc = 0.04419417382415922f * 1.4426950408889634f;  // E^-0.5 * log2(e)

  unsigned short* ws = (unsigned short*)d_ws;
  unsigned short* xb    = ws;                   // x bf16 [8192,256]; later maskp
  unsigned short* cb    = ws + 2097152;         // ctx bf16 [8192,512]; later Vt
  unsigned short* wkvb  = ws + 6291456;         // [wk;wv] bf16 [1024,512]
  unsigned short* wob   = ws + 6815744;         // w_out bf16 [256,512]
  unsigned short* wqin  = ws + 6946816;         // fused Q weight bf16 [512,256]
  float*          bqinb = (float*)(ws + 7077888);  // fused Q bias fp32 [512]
  unsigned short* Qb    = ws + 7208960;         // Q bf16 [8192,512]
  unsigned short* KVb   = ws + 11403264;        // [8192,1024] K||V
  unsigned short* Ob    = ws + 19791872;        // attn out bf16 [8192,512]
  unsigned int*   maskp = (unsigned int*)xb;    // bit mask (xb dead after qgemm)
  unsigned short* Vtb   = cb;                   // V^T (cb dead after kvpack)

  prep<<<6832, 256, 0, stream>>>(x, ctx, w_in, b_in, wq, bq, wk, wv, wo,
                                 xb, cb, wkvb, wob, wqin, bqinb, qsc);
  // Q[8192,512] = x . wqin^T + bqin   (K=256)
  gemm_bt<true, 128, 64, 2><<<dim3(64, 8), 256, 0, stream>>>(
      xb, wqin, bqinb, nullptr, 512, Qb, 8192, 512, 256);
  // KV gemm (compute-bound) overlapped with mask bit-pack (HBM-bound)
  kvpack<<<2560, 256, 0, stream>>>(cb, wkvb, bk, bv, KVb, mask, maskp);
  vtrans<<<dim3(32, 8, 4), 256, 0, stream>>>(KVb + 512, LDK, Vtb);
  attn<<<dim3(16, 8, 4), 256, 0, stream>>>(Qb, KVb, Vtb, maskp, Ob);
  gemm_bt<false, 64, 64, 2><<<dim3(128, 4), 256, 0, stream>>>(
      Ob, wob, bo, nullptr, 256, d_out, 8192, 256, 512);
}